// Round 4
// baseline (141.907 us; speedup 1.0000x reference)
//
#include <hip/hip_runtime.h>
#include <math.h>

#define CB_M 64      // codewords
#define CB_D 16      // vector dim
#define HARD 5.0f
#define LOG2E 1.44269504088896340736f
#define VPT 4        // vectors per thread

#if __has_builtin(__builtin_amdgcn_exp2f)
#define EXP2F(x) __builtin_amdgcn_exp2f(x)
#else
#define EXP2F(x) __expf((x) * 0.69314718055994530942f)
#endif

// ws layout: [0,64)   bias_m = -H*log2e*||r_m||^2
//            [64,...) R[m][j] = (2H*log2e) * ref[m][j], rows 64B-aligned
__global__ void stq_prep(const float* __restrict__ ref, float* __restrict__ ws) {
    int m = threadIdx.x;
    if (m >= CB_M) return;
    const float4* rp = (const float4*)(ref + m * CB_D);
    float4 a = rp[0], b = rp[1], c = rp[2], d = rp[3];
    float r2 = a.x*a.x + a.y*a.y + a.z*a.z + a.w*a.w
             + b.x*b.x + b.y*b.y + b.z*b.z + b.w*b.w
             + c.x*c.x + c.y*c.y + c.z*c.z + c.w*c.w
             + d.x*d.x + d.y*d.y + d.z*d.z + d.w*d.w;
    ws[m] = -(HARD * LOG2E) * r2;
    const float s = 2.0f * HARD * LOG2E;
    float4* op = (float4*)(ws + CB_M + m * CB_D);
    op[0] = make_float4(a.x*s, a.y*s, a.z*s, a.w*s);
    op[1] = make_float4(b.x*s, b.y*s, b.z*s, b.w*s);
    op[2] = make_float4(c.x*s, c.y*s, c.z*s, c.w*s);
    op[3] = make_float4(d.x*s, d.y*s, d.z*s, d.w*s);
}

// One thread owns VPT consecutive vectors. Online softmax in exp2 domain.
// Codebook reads are loop-uniform -> scalar loads (SGPR broadcast), no LDS.
__global__ __launch_bounds__(256, 3) void stq_main(const float* __restrict__ x,
                                                   const float* __restrict__ ws,
                                                   float* __restrict__ out,
                                                   int nvec) {
    const float* __restrict__ cb_bias = ws;         // [64]
    const float* __restrict__ cb      = ws + CB_M;  // [64][16], scaled

    const int p = blockIdx.x * blockDim.x + threadIdx.x;
    const int base = p * VPT;
    if (base >= nvec) return;

    float xv[VPT][CB_D];
    {
        const float4* xp = (const float4*)(x + (size_t)base * CB_D);
#pragma unroll
        for (int q = 0; q < VPT * 4; ++q) {
            float4 t = xp[q];
            xv[q >> 2][(q & 3) * 4 + 0] = t.x;
            xv[q >> 2][(q & 3) * 4 + 1] = t.y;
            xv[q >> 2][(q & 3) * 4 + 2] = t.z;
            xv[q >> 2][(q & 3) * 4 + 3] = t.w;
        }
    }

    float zv[VPT][CB_D];
    float tmax[VPT], den[VPT];
#pragma unroll
    for (int v = 0; v < VPT; ++v) {
        tmax[v] = -INFINITY;
        den[v] = 0.0f;
#pragma unroll
        for (int j = 0; j < CB_D; ++j) zv[v][j] = 0.0f;
    }

    for (int m = 0; m < CB_M; ++m) {
        const float bias = cb_bias[m];     // uniform -> s_load
        float r[CB_D];
#pragma unroll
        for (int j = 0; j < CB_D; ++j) r[j] = cb[m * CB_D + j];  // uniform -> s_load_dwordx16

#pragma unroll
        for (int v = 0; v < VPT; ++v) {
            float t = bias;
#pragma unroll
            for (int j = 0; j < CB_D; ++j) t = fmaf(xv[v][j], r[j], t);
            float nm = fmaxf(tmax[v], t);
            float al = EXP2F(tmax[v] - nm);   // exp2(-inf)=0 on first update
            float e  = EXP2F(t - nm);
            tmax[v] = nm;
            den[v] = fmaf(den[v], al, e);
#pragma unroll
            for (int j = 0; j < CB_D; ++j)
                zv[v][j] = fmaf(zv[v][j], al, e * r[j]);
        }
    }

    // z holds sum e * (2H*log2e * ref); output = z / (2H*log2e * den)
    const float s = 2.0f * HARD * LOG2E;
    float4* op = (float4*)(out + (size_t)base * CB_D);
#pragma unroll
    for (int v = 0; v < VPT; ++v) {
        float inv = 1.0f / (s * den[v]);
#pragma unroll
        for (int q = 0; q < 4; ++q) {
            op[v * 4 + q] = make_float4(zv[v][q*4+0] * inv, zv[v][q*4+1] * inv,
                                        zv[v][q*4+2] * inv, zv[v][q*4+3] * inv);
        }
    }
}

extern "C" void kernel_launch(void* const* d_in, const int* in_sizes, int n_in,
                              void* d_out, int out_size, void* d_ws, size_t ws_size,
                              hipStream_t stream) {
    const float* x   = (const float*)d_in[0];   // (64,8,32,32,16) f32
    const float* ref = (const float*)d_in[1];   // (64,16) f32
    float* out = (float*)d_out;
    float* ws  = (float*)d_ws;                  // needs (64 + 64*16)*4 = 4352 B

    const int nvec = in_sizes[0] / CB_D;        // 524288
    stq_prep<<<1, 64, 0, stream>>>(ref, ws);

    const int nthreads = (nvec + VPT - 1) / VPT;
    const int block = 256;
    const int grid = (nthreads + block - 1) / block;
    stq_main<<<grid, block, 0, stream>>>(x, ws, out, nvec);
}

// Round 5
// 95.868 us; speedup vs baseline: 1.4802x; 1.4802x over previous
//
#include <hip/hip_runtime.h>
#include <math.h>

#define CB_M 64      // codewords
#define CB_D 16      // vector dim
#define HARD 5.0f
#define LOG2E 1.44269504088896340736f
#define LDS_STRIDE 68   // dwords per S row: 16B-aligned, spreads banks (68%32=4)

typedef __attribute__((ext_vector_type(8))) short bf16x8;  // 8 bf16 = 4 VGPRs
typedef __attribute__((ext_vector_type(4))) float f32x4;

#if __has_builtin(__builtin_amdgcn_exp2f)
#define EXP2F(x) __builtin_amdgcn_exp2f(x)
#else
#define EXP2F(x) exp2f(x)
#endif

__device__ __forceinline__ ushort f2bf(float f) {
    unsigned u = __float_as_uint(f);
    u += 0x7fffu + ((u >> 16) & 1u);       // RNE
    return (ushort)(u >> 16);
}
__device__ __forceinline__ float bf2f(ushort h) {
    return __uint_as_float(((unsigned)h) << 16);
}

// ws layout (bytes):
//   0    : bias  f32[64]        bias_m = -H*log2e*||r_m||^2
//   256  : rs_hi u16[64][16]    bf16 hi of (2H*log2e)*r   (S-GEMM B)
//   2304 : rs_lo u16[64][16]    bf16 lo residual
//   4352 : rzT_hi u16[16][64]   bf16 hi of r, TRANSPOSED  (Z-GEMM B)
//   6400 : rzT_lo u16[16][64]   bf16 lo residual, transposed
__global__ void stq_prep(const float* __restrict__ ref, char* __restrict__ ws) {
    float*  bias   = (float*)(ws);
    ushort* rs_hi  = (ushort*)(ws + 256);
    ushort* rs_lo  = (ushort*)(ws + 2304);
    ushort* rzT_hi = (ushort*)(ws + 4352);
    ushort* rzT_lo = (ushort*)(ws + 6400);

    int m = threadIdx.x;
    if (m >= CB_M) return;
    float r[CB_D];
    float r2 = 0.0f;
    for (int j = 0; j < CB_D; ++j) { r[j] = ref[m * CB_D + j]; r2 += r[j] * r[j]; }
    bias[m] = -(HARD * LOG2E) * r2;
    const float s = 2.0f * HARD * LOG2E;
    for (int j = 0; j < CB_D; ++j) {
        float v = s * r[j];
        ushort h = f2bf(v);
        rs_hi[m * CB_D + j] = h;
        rs_lo[m * CB_D + j] = f2bf(v - bf2f(h));
        ushort zh = f2bf(r[j]);
        rzT_hi[j * CB_M + m] = zh;
        rzT_lo[j * CB_M + m] = f2bf(r[j] - bf2f(zh));
    }
}

// One wave processes 16 vectors (rows) per tile.
// S = X@R'^T via mfma 16x16x32 bf16, A=[x_hi|x_lo], B=[r_hi|r_hi]+[r_lo|r_lo]
// softmax rows via LDS C->A layout round-trip, Z = P@R via 4 mfma (R hi/lo).
__global__ __launch_bounds__(256, 3) void stq_main(const float* __restrict__ x,
                                                   const char* __restrict__ ws,
                                                   float* __restrict__ out,
                                                   int ntiles) {
    const float*  bias   = (const float*)(ws);
    const ushort* rs_hi  = (const ushort*)(ws + 256);
    const ushort* rs_lo  = (const ushort*)(ws + 2304);
    const ushort* rzT_hi = (const ushort*)(ws + 4352);
    const ushort* rzT_lo = (const ushort*)(ws + 6400);

    __shared__ float slds[4][16 * LDS_STRIDE];   // per-wave private S tile

    const int lane = threadIdx.x & 63;
    const int wid  = threadIdx.x >> 6;
    const int i = lane & 15;    // A-row / B-col index within fragment
    const int c = lane >> 4;    // k-octet selector (quad)
    float* S = slds[wid];

    // Resident B fragments (S-GEMM): codeword n = 16t+i, dims (c&1)*8..+8
    bf16x8 BsH[4], BsL[4];
    float biasv[4];
#pragma unroll
    for (int t = 0; t < 4; ++t) {
        biasv[t] = bias[16 * t + i];
        BsH[t] = *(const bf16x8*)(rs_hi + (16 * t + i) * CB_D + (c & 1) * 8);
        BsL[t] = *(const bf16x8*)(rs_lo + (16 * t + i) * CB_D + (c & 1) * 8);
    }
    // Resident B fragments (Z-GEMM): dim n = i, codewords k = c*8..+8 (+32)
    bf16x8 BzH0 = *(const bf16x8*)(rzT_hi + i * CB_M + c * 8);
    bf16x8 BzH1 = *(const bf16x8*)(rzT_hi + i * CB_M + 32 + c * 8);
    bf16x8 BzL0 = *(const bf16x8*)(rzT_lo + i * CB_M + c * 8);
    bf16x8 BzL1 = *(const bf16x8*)(rzT_lo + i * CB_M + 32 + c * 8);

    const int nwaves = gridDim.x * 4;
    for (int tile = blockIdx.x * 4 + wid; tile < ntiles; tile += nwaves) {
        const int rowbase = tile * 16;

        // ---- A fragment: lane holds x[row=i][8 dims], hi (c<2) or lo (c>=2)
        const float* xp = x + (size_t)(rowbase + i) * CB_D + (c & 1) * 8;
        f32x4 xa = *(const f32x4*)xp;
        f32x4 xb = *(const f32x4*)(xp + 4);
        float xf[8] = {xa.x, xa.y, xa.z, xa.w, xb.x, xb.y, xb.z, xb.w};
        const bool wantlo = (c >= 2);
        bf16x8 A;
#pragma unroll
        for (int j = 0; j < 8; ++j) {
            ushort h = f2bf(xf[j]);
            ushort l = f2bf(xf[j] - bf2f(h));
            A[j] = (short)(wantlo ? l : h);
        }

        // ---- S-GEMM: acc[t] = bias + (x_hi+x_lo).(r_hi+r_lo) scaled
        f32x4 acc[4];
#pragma unroll
        for (int t = 0; t < 4; ++t) {
            f32x4 cinit = {biasv[t], biasv[t], biasv[t], biasv[t]};
            acc[t] = __builtin_amdgcn_mfma_f32_16x16x32_bf16(A, BsH[t], cinit, 0, 0, 0);
            acc[t] = __builtin_amdgcn_mfma_f32_16x16x32_bf16(A, BsL[t], acc[t], 0, 0, 0);
        }

        // ---- C-layout -> LDS: lane writes rows 4c+r, col i+16t
#pragma unroll
        for (int t = 0; t < 4; ++t)
#pragma unroll
            for (int r = 0; r < 4; ++r)
                S[(4 * c + r) * LDS_STRIDE + i + 16 * t] = acc[t][r];

        // ---- read back in A-ish layout: row i, cols c*8..+8 and 32+c*8..+8
        float sv[16];
        {
            const f32x4* p0 = (const f32x4*)(S + i * LDS_STRIDE + c * 8);
            const f32x4* p1 = (const f32x4*)(S + i * LDS_STRIDE + 32 + c * 8);
            f32x4 a0 = p0[0], a1 = p0[1], b0 = p1[0], b1 = p1[1];
            sv[0]=a0.x; sv[1]=a0.y; sv[2]=a0.z; sv[3]=a0.w;
            sv[4]=a1.x; sv[5]=a1.y; sv[6]=a1.z; sv[7]=a1.w;
            sv[8]=b0.x; sv[9]=b0.y; sv[10]=b0.z; sv[11]=b0.w;
            sv[12]=b1.x; sv[13]=b1.y; sv[14]=b1.z; sv[15]=b1.w;
        }

        // ---- row softmax: the 4 lanes {i,16+i,32+i,48+i} hold row i's 64 vals
        float lmax = sv[0];
#pragma unroll
        for (int j = 1; j < 16; ++j) lmax = fmaxf(lmax, sv[j]);
        lmax = fmaxf(lmax, __shfl_xor(lmax, 16, 64));
        lmax = fmaxf(lmax, __shfl_xor(lmax, 32, 64));

        float e[16];
        float lsum = 0.0f;
#pragma unroll
        for (int j = 0; j < 16; ++j) { e[j] = EXP2F(sv[j] - lmax); lsum += e[j]; }
        lsum += __shfl_xor(lsum, 16, 64);
        lsum += __shfl_xor(lsum, 32, 64);
        const float inv = 1.0f / lsum;

        // ---- P fragments (A-layout already): y = e/den in bf16
        bf16x8 P1, P2;
#pragma unroll
        for (int j = 0; j < 8; ++j) {
            P1[j] = (short)f2bf(e[j] * inv);
            P2[j] = (short)f2bf(e[8 + j] * inv);
        }

        // ---- Z-GEMM: Z = P @ (R_hi + R_lo)
        f32x4 cz = {0.0f, 0.0f, 0.0f, 0.0f};
        cz = __builtin_amdgcn_mfma_f32_16x16x32_bf16(P1, BzH0, cz, 0, 0, 0);
        cz = __builtin_amdgcn_mfma_f32_16x16x32_bf16(P2, BzH1, cz, 0, 0, 0);
        cz = __builtin_amdgcn_mfma_f32_16x16x32_bf16(P1, BzL0, cz, 0, 0, 0);
        cz = __builtin_amdgcn_mfma_f32_16x16x32_bf16(P2, BzL1, cz, 0, 0, 0);

        // ---- store: lane holds Z[row=4c+r][dim=i]
#pragma unroll
        for (int r = 0; r < 4; ++r)
            out[(size_t)(rowbase + 4 * c + r) * CB_D + i] = cz[r];
    }
}

extern "C" void kernel_launch(void* const* d_in, const int* in_sizes, int n_in,
                              void* d_out, int out_size, void* d_ws, size_t ws_size,
                              hipStream_t stream) {
    const float* x   = (const float*)d_in[0];   // (64,8,32,32,16) f32
    const float* ref = (const float*)d_in[1];   // (64,16) f32
    float* out = (float*)d_out;
    char* ws = (char*)d_ws;                     // needs ~8.5 KB

    const int nvec = in_sizes[0] / CB_D;        // 524288
    const int ntiles = nvec / 16;               // 32768

    stq_prep<<<1, 64, 0, stream>>>(ref, ws);
    stq_main<<<1024, 256, 0, stream>>>(x, ws, out, ntiles);
}

// Round 6
// 89.698 us; speedup vs baseline: 1.5821x; 1.0688x over previous
//
#include <hip/hip_runtime.h>
#include <math.h>

#define CB_M 64      // codewords
#define CB_D 16      // vector dim
#define HARD 5.0f
#define LOG2E 1.44269504088896340736f
#define SSTRIDE 68   // dwords per S row in LDS (16B-aligned, 2-way banks only)

typedef __attribute__((ext_vector_type(8))) short bf16x8;  // 8 bf16 = 4 VGPRs
typedef __attribute__((ext_vector_type(4))) float f32x4;
typedef __attribute__((ext_vector_type(4))) int   i32x4;

#if __has_builtin(__builtin_amdgcn_exp2f)
#define EXP2F(x) __builtin_amdgcn_exp2f(x)
#else
#define EXP2F(x) exp2f(x)
#endif

#if __has_builtin(__builtin_amdgcn_rcpf)
#define RCPF(x) __builtin_amdgcn_rcpf(x)
#else
#define RCPF(x) (1.0f / (x))
#endif

__device__ __forceinline__ ushort f2bf_rne(float f) {
    unsigned u = __float_as_uint(f);
    u += 0x7fffu + ((u >> 16) & 1u);       // RNE (prep path only)
    return (ushort)(u >> 16);
}
__device__ __forceinline__ float bf2f(ushort h) {
    return __uint_as_float(((unsigned)h) << 16);
}
// pack [bf16(a) : bf16(b)] into one dword (a = high half), TRUNCATING.
__device__ __forceinline__ int pk(float a, float b) {
    return (int)__builtin_amdgcn_perm(__float_as_uint(a), __float_as_uint(b), 0x07060302u);
}
// half-ulp bump so a following truncation is round-to-nearest(-half-up)
__device__ __forceinline__ float rnd(float a) {
    return __uint_as_float(__float_as_uint(a) + 0x8000u);
}
// truncate float to bf16 value (keep top 16 bits) — for exact residual split
__device__ __forceinline__ float hi_trunc(float a) {
    return __uint_as_float(__float_as_uint(a) & 0xffff0000u);
}

// Single fused kernel. Wave-private 16-row tiles:
//   S = [bias] + Xsplit @ R'^T  (2 mfma per 16-codeword block, hi/lo split)
//   row softmax (exp2 domain) via LDS C->A layout round-trip + 4 shfl
//   Z = P @ (R_hi + R_lo)       (4 mfma)
// Codebook is prepped into LDS by threads 0..63 once per block.
__global__ __launch_bounds__(256, 2) void stq_main(const float* __restrict__ x,
                                                   const float* __restrict__ ref,
                                                   float* __restrict__ out,
                                                   int ntiles) {
    __shared__ __align__(16) float  cb_bias[CB_M];
    __shared__ __align__(16) ushort cb_rs_hi[CB_M][CB_D];   // (2H*log2e)*r hi
    __shared__ __align__(16) ushort cb_rs_lo[CB_M][CB_D];   // residual
    __shared__ __align__(16) ushort cb_rzT_hi[CB_D][CB_M];  // r^T hi
    __shared__ __align__(16) ushort cb_rzT_lo[CB_D][CB_M];  // residual
    __shared__ __align__(16) float  slds[4][16 * SSTRIDE];  // per-wave S tile

    const int tid = threadIdx.x;

    // ---- block-local codebook prep (wave 0) ----
    if (tid < CB_M) {
        const f32x4* rp = (const f32x4*)(ref + tid * CB_D);
        f32x4 q0 = rp[0], q1 = rp[1], q2 = rp[2], q3 = rp[3];
        float r[CB_D] = {q0.x,q0.y,q0.z,q0.w, q1.x,q1.y,q1.z,q1.w,
                         q2.x,q2.y,q2.z,q2.w, q3.x,q3.y,q3.z,q3.w};
        float r2 = 0.0f;
#pragma unroll
        for (int j = 0; j < CB_D; ++j) r2 += r[j] * r[j];
        cb_bias[tid] = -(HARD * LOG2E) * r2;
        const float s = 2.0f * HARD * LOG2E;
#pragma unroll
        for (int j = 0; j < CB_D; ++j) {
            float v = s * r[j];
            ushort h = f2bf_rne(v);
            cb_rs_hi[tid][j] = h;
            cb_rs_lo[tid][j] = f2bf_rne(v - bf2f(h));
            ushort zh = f2bf_rne(r[j]);
            cb_rzT_hi[j][tid] = zh;
            cb_rzT_lo[j][tid] = f2bf_rne(r[j] - bf2f(zh));
        }
    }
    __syncthreads();

    const int lane = tid & 63;
    const int wid  = tid >> 6;
    const int i = lane & 15;        // fragment row/col index
    const int c = lane >> 4;        // k-octet quad
    const bool wantlo = (c >= 2);
    float* S = slds[wid];

    // ---- resident fragments ----
    bf16x8 BsH[4], BsL[4];
    f32x4  cinit[4];                // loop-invariant bias splats (C operand)
#pragma unroll
    for (int t = 0; t < 4; ++t) {
        float b = cb_bias[16 * t + i];
        cinit[t] = (f32x4){b, b, b, b};
        BsH[t] = *(const bf16x8*)&cb_rs_hi[16 * t + i][(c & 1) * 8];
        BsL[t] = *(const bf16x8*)&cb_rs_lo[16 * t + i][(c & 1) * 8];
    }
    bf16x8 BzH0 = *(const bf16x8*)&cb_rzT_hi[i][c * 8];
    bf16x8 BzH1 = *(const bf16x8*)&cb_rzT_hi[i][32 + c * 8];
    bf16x8 BzL0 = *(const bf16x8*)&cb_rzT_lo[i][c * 8];
    bf16x8 BzL1 = *(const bf16x8*)&cb_rzT_lo[i][32 + c * 8];

    const int nwaves = gridDim.x * 4;
    int tile = blockIdx.x * 4 + wid;

    // ---- prefetch first tile ----
    f32x4 nxa, nxb;
    {
        const float* xp = x + ((size_t)tile * 16 + i) * CB_D + (c & 1) * 8;
        nxa = *(const f32x4*)xp;
        nxb = *(const f32x4*)(xp + 4);
    }

#pragma unroll 1
    for (; tile < ntiles; tile += nwaves) {
        f32x4 xa = nxa, xb = nxb;
        const int nt = tile + nwaves;
        if (nt < ntiles) {
            const float* xp = x + ((size_t)nt * 16 + i) * CB_D + (c & 1) * 8;
            nxa = *(const f32x4*)xp;
            nxb = *(const f32x4*)(xp + 4);
        }

        // ---- A fragment: hi = trunc top16 (1 perm/pair), lo = rounded residual
        i32x4 Ahi, Alo;
        Ahi.x = pk(xa.y, xa.x); Ahi.y = pk(xa.w, xa.z);
        Ahi.z = pk(xb.y, xb.x); Ahi.w = pk(xb.w, xb.z);
        float l0 = xa.x - hi_trunc(xa.x), l1 = xa.y - hi_trunc(xa.y);
        float l2 = xa.z - hi_trunc(xa.z), l3 = xa.w - hi_trunc(xa.w);
        float l4 = xb.x - hi_trunc(xb.x), l5 = xb.y - hi_trunc(xb.y);
        float l6 = xb.z - hi_trunc(xb.z), l7 = xb.w - hi_trunc(xb.w);
        Alo.x = pk(rnd(l1), rnd(l0)); Alo.y = pk(rnd(l3), rnd(l2));
        Alo.z = pk(rnd(l5), rnd(l4)); Alo.w = pk(rnd(l7), rnd(l6));
        i32x4 Ai;
        Ai.x = wantlo ? Alo.x : Ahi.x;
        Ai.y = wantlo ? Alo.y : Ahi.y;
        Ai.z = wantlo ? Alo.z : Ahi.z;
        Ai.w = wantlo ? Alo.w : Ahi.w;
        bf16x8 A = __builtin_bit_cast(bf16x8, Ai);

        // ---- S-GEMM: acc[t] = bias + (Xhi+Xlo).(Rhi+Rlo), scaled log2 domain
        f32x4 acc[4];
#pragma unroll
        for (int t = 0; t < 4; ++t) {
            acc[t] = __builtin_amdgcn_mfma_f32_16x16x32_bf16(A, BsH[t], cinit[t], 0, 0, 0);
            acc[t] = __builtin_amdgcn_mfma_f32_16x16x32_bf16(A, BsL[t], acc[t], 0, 0, 0);
        }

        // ---- C-layout -> LDS (lane writes rows 4c+r, col i+16t)
#pragma unroll
        for (int t = 0; t < 4; ++t)
#pragma unroll
            for (int r = 0; r < 4; ++r)
                S[(4 * c + r) * SSTRIDE + i + 16 * t] = acc[t][r];

        // ---- read back A-layout: row i, cols c*8..+8 and 32+c*8..+8
        float sv[16];
        {
            const f32x4* p0 = (const f32x4*)(S + i * SSTRIDE + c * 8);
            const f32x4* p1 = (const f32x4*)(S + i * SSTRIDE + 32 + c * 8);
            f32x4 a0 = p0[0], a1 = p0[1], b0 = p1[0], b1 = p1[1];
            sv[0]=a0.x; sv[1]=a0.y; sv[2]=a0.z; sv[3]=a0.w;
            sv[4]=a1.x; sv[5]=a1.y; sv[6]=a1.z; sv[7]=a1.w;
            sv[8]=b0.x; sv[9]=b0.y; sv[10]=b0.z; sv[11]=b0.w;
            sv[12]=b1.x; sv[13]=b1.y; sv[14]=b1.z; sv[15]=b1.w;
        }

        // ---- row softmax over 64 codewords (lanes {i,16+i,32+i,48+i})
        float lmax = sv[0];
#pragma unroll
        for (int j = 1; j < 16; ++j) lmax = fmaxf(lmax, sv[j]);
        lmax = fmaxf(lmax, __shfl_xor(lmax, 16, 64));
        lmax = fmaxf(lmax, __shfl_xor(lmax, 32, 64));

        float e[16];
        float lsum = 0.0f;
#pragma unroll
        for (int j = 0; j < 16; ++j) { e[j] = EXP2F(sv[j] - lmax); lsum += e[j]; }
        lsum += __shfl_xor(lsum, 16, 64);
        lsum += __shfl_xor(lsum, 32, 64);
        const float inv = RCPF(lsum);

        // ---- P fragments (already A-layout), rounded-truncate pack
        i32x4 P1i, P2i;
        P1i.x = pk(rnd(e[1] * inv),  rnd(e[0] * inv));
        P1i.y = pk(rnd(e[3] * inv),  rnd(e[2] * inv));
        P1i.z = pk(rnd(e[5] * inv),  rnd(e[4] * inv));
        P1i.w = pk(rnd(e[7] * inv),  rnd(e[6] * inv));
        P2i.x = pk(rnd(e[9] * inv),  rnd(e[8] * inv));
        P2i.y = pk(rnd(e[11] * inv), rnd(e[10] * inv));
        P2i.z = pk(rnd(e[13] * inv), rnd(e[12] * inv));
        P2i.w = pk(rnd(e[15] * inv), rnd(e[14] * inv));
        bf16x8 P1 = __builtin_bit_cast(bf16x8, P1i);
        bf16x8 P2 = __builtin_bit_cast(bf16x8, P2i);

        // ---- Z-GEMM: Z = P @ (R_hi + R_lo)
        f32x4 cz = {0.0f, 0.0f, 0.0f, 0.0f};
        cz = __builtin_amdgcn_mfma_f32_16x16x32_bf16(P1, BzH0, cz, 0, 0, 0);
        cz = __builtin_amdgcn_mfma_f32_16x16x32_bf16(P2, BzH1, cz, 0, 0, 0);
        cz = __builtin_amdgcn_mfma_f32_16x16x32_bf16(P1, BzL0, cz, 0, 0, 0);
        cz = __builtin_amdgcn_mfma_f32_16x16x32_bf16(P2, BzL1, cz, 0, 0, 0);

        // ---- store: lane holds Z[row 4c+r][dim i]
        const int rowbase = tile * 16;
#pragma unroll
        for (int r = 0; r < 4; ++r)
            out[(size_t)(rowbase + 4 * c + r) * CB_D + i] = cz[r];
    }
}

extern "C" void kernel_launch(void* const* d_in, const int* in_sizes, int n_in,
                              void* d_out, int out_size, void* d_ws, size_t ws_size,
                              hipStream_t stream) {
    const float* x   = (const float*)d_in[0];   // (64,8,32,32,16) f32
    const float* ref = (const float*)d_in[1];   // (64,16) f32
    float* out = (float*)d_out;

    const int nvec = in_sizes[0] / CB_D;        // 524288
    const int ntiles = nvec / 16;               // 32768

    stq_main<<<1024, 256, 0, stream>>>(x, ref, out, ntiles);
}

// Round 7
// 88.737 us; speedup vs baseline: 1.5992x; 1.0108x over previous
//
#include <hip/hip_runtime.h>
#include <math.h>

#define CB_M 64      // codewords
#define CB_D 16      // vector dim
#define HARD 5.0f
#define LOG2E 1.44269504088896340736f

typedef __attribute__((ext_vector_type(8))) short bf16x8;  // 8 bf16 = 4 VGPRs
typedef __attribute__((ext_vector_type(4))) float f32x4;
typedef __attribute__((ext_vector_type(4))) int   i32x4;

#if __has_builtin(__builtin_amdgcn_exp2f)
#define EXP2F(x) __builtin_amdgcn_exp2f(x)
#else
#define EXP2F(x) exp2f(x)
#endif

#if __has_builtin(__builtin_amdgcn_rcpf)
#define RCPF(x) __builtin_amdgcn_rcpf(x)
#else
#define RCPF(x) (1.0f / (x))
#endif

__device__ __forceinline__ ushort f2bf_rne(float f) {
    unsigned u = __float_as_uint(f);
    u += 0x7fffu + ((u >> 16) & 1u);       // RNE (prep path only)
    return (ushort)(u >> 16);
}
__device__ __forceinline__ float bf2f(ushort h) {
    return __uint_as_float(((unsigned)h) << 16);
}
// pack [bf16(a) : bf16(b)] into one dword (a = high half), TRUNCATING
__device__ __forceinline__ int pk(float a, float b) {
    return (int)__builtin_amdgcn_perm(__float_as_uint(a), __float_as_uint(b), 0x07060302u);
}
// half-ulp bump so a following truncation rounds to nearest
__device__ __forceinline__ float rnd(float a) {
    return __uint_as_float(__float_as_uint(a) + 0x8000u);
}
// truncate float to bf16 value (exact residual split)
__device__ __forceinline__ float hi_trunc(float a) {
    return __uint_as_float(__float_as_uint(a) & 0xffff0000u);
}

// Transposed-S formulation, no per-tile LDS:
//   S^T = Rperm @ Xsplit  (codebook is the A operand; codeword->A-row
//   permutation cw(t,m)=32(t>>1)+8(m>>2)+4(t&1)+(m&3) makes the softmaxed
//   C-layout registers EXACTLY the A-operand layout for the Z-GEMM)
//   softmax per vector-row: 16 per-lane values + 2 shfl_xor
//   Z = P @ (R_hi + R_lo)
__global__ __launch_bounds__(256, 2) void stq_main(const float* __restrict__ x,
                                                   const float* __restrict__ ref,
                                                   float* __restrict__ out,
                                                   int ntiles) {
    __shared__ __align__(16) float  cb_bias[CB_M];
    __shared__ __align__(16) ushort cb_rs_hi[CB_M][CB_D];   // (2H*log2e)*r hi
    __shared__ __align__(16) ushort cb_rs_lo[CB_M][CB_D];   // residual
    __shared__ __align__(16) ushort cb_rzT_hi[CB_D][CB_M];  // r^T hi
    __shared__ __align__(16) ushort cb_rzT_lo[CB_D][CB_M];  // residual

    const int tid = threadIdx.x;

    // ---- block-local codebook prep (threads 0..63) ----
    if (tid < CB_M) {
        const f32x4* rp = (const f32x4*)(ref + tid * CB_D);
        f32x4 q0 = rp[0], q1 = rp[1], q2 = rp[2], q3 = rp[3];
        float r[CB_D] = {q0.x,q0.y,q0.z,q0.w, q1.x,q1.y,q1.z,q1.w,
                         q2.x,q2.y,q2.z,q2.w, q3.x,q3.y,q3.z,q3.w};
        float r2 = 0.0f;
#pragma unroll
        for (int j = 0; j < CB_D; ++j) r2 += r[j] * r[j];
        cb_bias[tid] = -(HARD * LOG2E) * r2;
        const float s = 2.0f * HARD * LOG2E;
#pragma unroll
        for (int j = 0; j < CB_D; ++j) {
            float v = s * r[j];
            ushort h = f2bf_rne(v);
            cb_rs_hi[tid][j] = h;
            cb_rs_lo[tid][j] = f2bf_rne(v - bf2f(h));
            ushort zh = f2bf_rne(r[j]);
            cb_rzT_hi[j][tid] = zh;
            cb_rzT_lo[j][tid] = f2bf_rne(r[j] - bf2f(zh));
        }
    }
    __syncthreads();

    const int lane = tid & 63;
    const int wid  = tid >> 6;
    const int i = lane & 15;        // fragment n-index (vector row / Z dim)
    const int c = lane >> 4;        // k-octet quad

    // ---- resident fragments ----
    // S-GEMM A operand (codebook), permuted row order. Lane holds A_t[row i]:
    //   A1 = [r_hi dims | r_lo dims] across quads, A2 = [r_hi | 0]
    bf16x8 A1[4], A2[4];
    f32x4  cinit[4];
    bf16x8 zfrag;
#pragma unroll
    for (int j = 0; j < 8; ++j) zfrag[j] = 0;
#pragma unroll
    for (int t = 0; t < 4; ++t) {
        const int cwa = 32 * (t >> 1) + 8 * (i >> 2) + 4 * (t & 1) + (i & 3);
        const ushort* src = (c < 2) ? &cb_rs_hi[cwa][0] : &cb_rs_lo[cwa][0];
        A1[t] = *(const bf16x8*)(src + (c & 1) * 8);
        A2[t] = (c < 2) ? A1[t] : zfrag;
#pragma unroll
        for (int r = 0; r < 4; ++r)
            cinit[t][r] = cb_bias[32 * (t >> 1) + 8 * c + 4 * (t & 1) + r];
    }
    // Z-GEMM B operand: R[cw][dim=i], cw blocks c*8.. and 32+c*8..
    bf16x8 BzH0 = *(const bf16x8*)&cb_rzT_hi[i][c * 8];
    bf16x8 BzH1 = *(const bf16x8*)&cb_rzT_hi[i][32 + c * 8];
    bf16x8 BzL0 = *(const bf16x8*)&cb_rzT_lo[i][c * 8];
    bf16x8 BzL1 = *(const bf16x8*)&cb_rzT_lo[i][32 + c * 8];

    const int nwaves = gridDim.x * 4;
    int tile = blockIdx.x * 4 + wid;

    // ---- prefetch first tile: lane loads x[row i][dims (c&1)*8..+8] ----
    f32x4 nxa, nxb;
    {
        const float* xp = x + ((size_t)tile * 16 + i) * CB_D + (c & 1) * 8;
        nxa = *(const f32x4*)xp;
        nxb = *(const f32x4*)(xp + 4);
    }

#pragma unroll 1
    for (; tile < ntiles; tile += nwaves) {
        f32x4 xa = nxa, xb = nxb;
        const int nt = tile + nwaves;
        if (nt < ntiles) {
            const float* xp = x + ((size_t)nt * 16 + i) * CB_D + (c & 1) * 8;
            nxa = *(const f32x4*)xp;
            nxb = *(const f32x4*)(xp + 4);
        }

        // ---- B fragments: B1 = x_hi (trunc), B2 = rounded residual ----
        i32x4 B1i, B2i;
        B1i.x = pk(xa.y, xa.x); B1i.y = pk(xa.w, xa.z);
        B1i.z = pk(xb.y, xb.x); B1i.w = pk(xb.w, xb.z);
        float l0 = xa.x - hi_trunc(xa.x), l1 = xa.y - hi_trunc(xa.y);
        float l2 = xa.z - hi_trunc(xa.z), l3 = xa.w - hi_trunc(xa.w);
        float l4 = xb.x - hi_trunc(xb.x), l5 = xb.y - hi_trunc(xb.y);
        float l6 = xb.z - hi_trunc(xb.z), l7 = xb.w - hi_trunc(xb.w);
        B2i.x = pk(rnd(l1), rnd(l0)); B2i.y = pk(rnd(l3), rnd(l2));
        B2i.z = pk(rnd(l5), rnd(l4)); B2i.w = pk(rnd(l7), rnd(l6));
        bf16x8 B1 = __builtin_bit_cast(bf16x8, B1i);
        bf16x8 B2 = __builtin_bit_cast(bf16x8, B2i);

        // ---- S^T GEMM: acc[t][r] = logit[cw 32(t>>1)+8c+4(t&1)+r][row i]
        f32x4 acc[4];
#pragma unroll
        for (int t = 0; t < 4; ++t) {
            acc[t] = __builtin_amdgcn_mfma_f32_16x16x32_bf16(A1[t], B1, cinit[t], 0, 0, 0);
            acc[t] = __builtin_amdgcn_mfma_f32_16x16x32_bf16(A2[t], B2, acc[t], 0, 0, 0);
        }

        // ---- row softmax: lane has 16 of row i's logits; lanes {i,16+i,32+i,48+i}
        float lmax = acc[0][0];
#pragma unroll
        for (int t = 0; t < 4; ++t)
#pragma unroll
            for (int r = 0; r < 4; ++r) lmax = fmaxf(lmax, acc[t][r]);
        lmax = fmaxf(lmax, __shfl_xor(lmax, 16, 64));
        lmax = fmaxf(lmax, __shfl_xor(lmax, 32, 64));

        float e[4][4];
        float lsum = 0.0f;
#pragma unroll
        for (int t = 0; t < 4; ++t)
#pragma unroll
            for (int r = 0; r < 4; ++r) { e[t][r] = EXP2F(acc[t][r] - lmax); lsum += e[t][r]; }
        lsum += __shfl_xor(lsum, 16, 64);
        lsum += __shfl_xor(lsum, 32, 64);
        const float inv = RCPF(lsum);

        // ---- P fragments: ALREADY in Z-GEMM A-layout thanks to the
        //      codeword permutation. P1[j=4t+r]=e[t][r] (t<2), P2: t>=2.
        i32x4 P1i, P2i;
        P1i.x = pk(rnd(e[0][1] * inv), rnd(e[0][0] * inv));
        P1i.y = pk(rnd(e[0][3] * inv), rnd(e[0][2] * inv));
        P1i.z = pk(rnd(e[1][1] * inv), rnd(e[1][0] * inv));
        P1i.w = pk(rnd(e[1][3] * inv), rnd(e[1][2] * inv));
        P2i.x = pk(rnd(e[2][1] * inv), rnd(e[2][0] * inv));
        P2i.y = pk(rnd(e[2][3] * inv), rnd(e[2][2] * inv));
        P2i.z = pk(rnd(e[3][1] * inv), rnd(e[3][0] * inv));
        P2i.w = pk(rnd(e[3][3] * inv), rnd(e[3][2] * inv));
        bf16x8 P1 = __builtin_bit_cast(bf16x8, P1i);
        bf16x8 P2 = __builtin_bit_cast(bf16x8, P2i);

        // ---- Z-GEMM: Z = P @ (R_hi + R_lo), two independent chains
        f32x4 z0 = {0.0f, 0.0f, 0.0f, 0.0f};
        f32x4 z1 = {0.0f, 0.0f, 0.0f, 0.0f};
        z0 = __builtin_amdgcn_mfma_f32_16x16x32_bf16(P1, BzH0, z0, 0, 0, 0);
        z1 = __builtin_amdgcn_mfma_f32_16x16x32_bf16(P1, BzL0, z1, 0, 0, 0);
        z0 = __builtin_amdgcn_mfma_f32_16x16x32_bf16(P2, BzH1, z0, 0, 0, 0);
        z1 = __builtin_amdgcn_mfma_f32_16x16x32_bf16(P2, BzL1, z1, 0, 0, 0);

        // ---- store: lane holds Z[row 4c+r][dim i]
        const int rowbase = tile * 16;
#pragma unroll
        for (int r = 0; r < 4; ++r)
            out[(size_t)(rowbase + 4 * c + r) * CB_D + i] = z0[r] + z1[r];
    }
}

extern "C" void kernel_launch(void* const* d_in, const int* in_sizes, int n_in,
                              void* d_out, int out_size, void* d_ws, size_t ws_size,
                              hipStream_t stream) {
    const float* x   = (const float*)d_in[0];   // (64,8,32,32,16) f32
    const float* ref = (const float*)d_in[1];   // (64,16) f32
    float* out = (float*)d_out;

    const int nvec = in_sizes[0] / CB_D;        // 524288
    const int ntiles = nvec / 16;               // 32768

    stq_main<<<1024, 256, 0, stream>>>(x, ref, out, ntiles);
}